// Round 1
// baseline (241.391 us; speedup 1.0000x reference)
//
#include <hip/hip_runtime.h>

#define N_NODES 4096
#define N_EDGES 131072
#define BATCH   16
#define HDIM    16
#define FCDIM   20
#define BH      256              // BATCH*HDIM
#define ISD     0.17677669529663687f  // 1/sqrt(E/N) = 1/sqrt(32)

// ---------------- setup: ew (3 per layer), G[b][j][k], invF, zero d_out ----
__global__ void setup_kernel(const float* __restrict__ F, const float* __restrict__ W_in,
                             const float* __restrict__ fc1_0, const float* __restrict__ fc2_0,
                             const float* __restrict__ fc1_1, const float* __restrict__ fc2_1,
                             float* __restrict__ ew, float* __restrict__ G,
                             float* __restrict__ invF, float* __restrict__ out144) {
    int t = threadIdx.x;
    if (t < 6) {
        const float* fc1 = (t < 3) ? fc1_0 : fc1_1;
        const float* fc2 = (t < 3) ? fc2_0 : fc2_1;
        int ty = t % 3;
        float s = 0.f;
        for (int f = 0; f < FCDIM; ++f) {
            float v = fc1[ty * FCDIM + f];
            v = v > 0.f ? v : 0.f;
            s += v * fc2[f];
        }
        ew[t] = s;
    }
    // G[b][j][k] = sum_i F[b][i][j] * W_in[i][k]   (768 entries)
    for (int idx = t; idx < BATCH * 3 * HDIM; idx += 256) {
        int b = idx / 48, r = idx % 48, j = r / HDIM, k = r % HDIM;
        float s = 0.f;
        for (int i = 0; i < 3; ++i) s += F[b * 9 + i * 3 + j] * W_in[i * HDIM + k];
        G[idx] = s;
    }
    if (t < BATCH) {
        const float* f = F + t * 9;
        float a00=f[0],a01=f[1],a02=f[2],a10=f[3],a11=f[4],a12=f[5],a20=f[6],a21=f[7],a22=f[8];
        float det = a00*(a11*a22-a12*a21) - a01*(a10*a22-a12*a20) + a02*(a10*a21-a11*a20);
        float id = 1.f/det;
        float* o = invF + t*9;
        o[0]=(a11*a22-a12*a21)*id; o[1]=(a02*a21-a01*a22)*id; o[2]=(a01*a12-a02*a11)*id;
        o[3]=(a12*a20-a10*a22)*id; o[4]=(a00*a22-a02*a20)*id; o[5]=(a02*a10-a00*a12)*id;
        o[6]=(a10*a21-a11*a20)*id; o[7]=(a01*a20-a00*a21)*id; o[8]=(a00*a11-a01*a10)*id;
    }
    if (t < 144) out144[t] = 0.f;
}

// ---------------- h0[n][b*16+k] = sum_j pos[n][j] * G[b][j][k] --------------
__global__ void h0_kernel(const float* __restrict__ pos, const float* __restrict__ G,
                          float* __restrict__ h0) {
    int id = blockIdx.x * 256 + threadIdx.x;   // 0..262143 (float4 units)
    int n  = id >> 6;
    int c4 = (id & 63) << 2;                   // column 0..255, step 4
    int b  = c4 >> 4;
    int k  = c4 & 15;
    float p0 = pos[n*3+0], p1 = pos[n*3+1], p2 = pos[n*3+2];
    const float* g = G + b*48 + k;
    float4 r;
    r.x = p0*g[0] + p1*g[16] + p2*g[32];
    r.y = p0*g[1] + p1*g[17] + p2*g[33];
    r.z = p0*g[2] + p1*g[18] + p2*g[34];
    r.w = p0*g[3] + p1*g[19] + p2*g[35];
    *(float4*)(h0 + n*BH + c4) = r;
}

// ---------------- CSR build -------------------------------------------------
__global__ void zero_kernel(int* p, int n) {
    int id = blockIdx.x * 256 + threadIdx.x;
    if (id < n) p[id] = 0;
}
__global__ void hist_kernel(const int* __restrict__ dst, int* __restrict__ cnt) {
    int e = blockIdx.x * 256 + threadIdx.x;
    if (e < N_EDGES) atomicAdd(&cnt[dst[e]], 1);
}
__global__ void scan_kernel(const int* __restrict__ cnt, int* __restrict__ off,
                            int* __restrict__ cursor) {
    __shared__ int part[256];
    __shared__ int pref[257];
    int t = threadIdx.x;
    int base = t * 16;
    int loc[16];
    int s = 0;
    #pragma unroll
    for (int i = 0; i < 16; ++i) { loc[i] = s; s += cnt[base + i]; }
    part[t] = s;
    __syncthreads();
    if (t == 0) {
        int acc = 0;
        for (int i = 0; i < 256; ++i) { pref[i] = acc; acc += part[i]; }
        pref[256] = acc;
    }
    __syncthreads();
    int p = pref[t];
    #pragma unroll
    for (int i = 0; i < 16; ++i) {
        int v = p + loc[i];
        off[base + i] = v;
        cursor[base + i] = v;
    }
    if (t == 0) off[N_NODES] = pref[256];
}
__global__ void fill_kernel(const int* __restrict__ src, const int* __restrict__ dst,
                            const int* __restrict__ typ, int* __restrict__ cursor,
                            int* __restrict__ sedge) {
    int e = blockIdx.x * 256 + threadIdx.x;
    if (e < N_EDGES) {
        int p = atomicAdd(&cursor[dst[e]], 1);
        sedge[p] = src[e] | (typ[e] << 16);   // pack src (12b) + type (2b)
    }
}

// ---------------- one GCN layer: gather+scale, @W, relu ---------------------
// one wave per dst node; lane owns 4 consecutive (b,k) columns
__global__ void layer_kernel(const float* __restrict__ h_in, float* __restrict__ h_out,
                             const int* __restrict__ off, const int* __restrict__ sedge,
                             const float* __restrict__ ew3, const float* __restrict__ W) {
    __shared__ float Wl[256];
    __shared__ float aggS[4][16*17 + 4];
    int t = threadIdx.x;
    Wl[t] = W[t];
    int wave = t >> 6;
    int lane = t & 63;
    int d = blockIdx.x * 4 + wave;
    float e0 = ew3[0], e1 = ew3[1], e2 = ew3[2];
    int beg = off[d], end = off[d+1];
    int col = lane << 2;
    float4 acc = {0.f, 0.f, 0.f, 0.f};
    for (int it = beg; it < end; ++it) {
        int v  = sedge[it];
        int s  = v & 0xFFFF;
        int ty = v >> 16;
        float wgt = (ty == 0) ? e0 : (ty == 1 ? e1 : e2);
        const float4 hv = *(const float4*)(h_in + s*BH + col);
        acc.x += wgt*hv.x; acc.y += wgt*hv.y; acc.z += wgt*hv.z; acc.w += wgt*hv.w;
    }
    int b = col >> 4, k0 = col & 15;
    float* as = aggS[wave];
    as[b*17 + k0+0] = acc.x * ISD;
    as[b*17 + k0+1] = acc.y * ISD;
    as[b*17 + k0+2] = acc.z * ISD;
    as[b*17 + k0+3] = acc.w * ISD;
    __syncthreads();
    const float* arow = as + b*17;
    float o0=0.f, o1=0.f, o2=0.f, o3=0.f;
    #pragma unroll
    for (int k = 0; k < 16; ++k) {
        float av = arow[k];
        const float* wr = Wl + k*16 + k0;
        o0 += av*wr[0]; o1 += av*wr[1]; o2 += av*wr[2]; o3 += av*wr[3];
    }
    float4 r;
    r.x = o0>0.f?o0:0.f; r.y = o1>0.f?o1:0.f; r.z = o2>0.f?o2:0.f; r.w = o3>0.f?o3:0.f;
    *(float4*)(h_out + d*BH + col) = r;
}

// ---------------- hout[n][b*3+p] = sum_k h2[n][b*16+k] * W_out[k][p] --------
__global__ void hout_kernel(const float* __restrict__ h2, const float* __restrict__ Wout,
                            float* __restrict__ hout) {
    __shared__ float Wo[48];
    int t = threadIdx.x;
    if (t < 48) Wo[t] = Wout[t];
    __syncthreads();
    int id = blockIdx.x * 256 + t;   // 0..65535
    int n = id >> 4, b = id & 15;
    const float* hr = h2 + n*BH + b*HDIM;
    float s0=0.f, s1=0.f, s2=0.f;
    #pragma unroll
    for (int k = 0; k < 16; ++k) {
        float v = hr[k];
        s0 += v*Wo[k*3+0]; s1 += v*Wo[k*3+1]; s2 += v*Wo[k*3+2];
    }
    float* o = hout + n*48 + b*3;
    o[0]=s0; o[1]=s1; o[2]=s2;
}

// ---------------- a, c for first N edges ------------------------------------
__global__ void ac_kernel(const float* __restrict__ hout, const int* __restrict__ esrc,
                          const int* __restrict__ edst, const float* __restrict__ invF,
                          float* __restrict__ a, float* __restrict__ c) {
    __shared__ float iF[144];
    int t = threadIdx.x;
    if (t < 144) iF[t] = invF[t];
    __syncthreads();
    int id = blockIdx.x * 256 + t;   // 0..65535
    int i = id >> 4, b = id & 15;
    int s = esrc[i], d = edst[i];
    float a0 = hout[s*48+b*3+0] - hout[d*48+b*3+0];
    float a1 = hout[s*48+b*3+1] - hout[d*48+b*3+1];
    float a2 = hout[s*48+b*3+2] - hout[d*48+b*3+2];
    float* ap = a + i*48 + b*3;
    ap[0]=a0; ap[1]=a1; ap[2]=a2;
    const float* m = iF + b*9;
    float* cp = c + i*48 + b*3;
    cp[0] = m[0]*a0 + m[1]*a1 + m[2]*a2;
    cp[1] = m[3]*a0 + m[4]*a1 + m[5]*a2;
    cp[2] = m[6]*a0 + m[7]*a1 + m[8]*a2;
}

// ---------------- stress[b,p,q] = sum_{i,j} W2[i,j] a[i,(b,p)] c[j,(b,q)] ---
// block: 256 j (thread-per-j), 128-row i strip; t[j][48] -> LDS -> 144 outputs
__global__ void stress_kernel(const float* __restrict__ W2, const float* __restrict__ a,
                              const float* __restrict__ c, float* __restrict__ out) {
    __shared__ float sh[256*49 + 2];   // padded stride 49 to dodge bank conflicts
    int t  = threadIdx.x;
    int jb = (blockIdx.x & 15) * 256;
    int ib = (blockIdx.x >> 4) * 128;
    int j  = jb + t;
    float acc[48];
    #pragma unroll
    for (int cI = 0; cI < 48; ++cI) acc[cI] = 0.f;
    const float* w2p = W2 + (size_t)ib * N_NODES + j;
    for (int ii = 0; ii < 128; ++ii) {
        float wv = w2p[(size_t)ii * N_NODES];
        const float4* ar = (const float4*)(a + (size_t)(ib + ii) * 48); // wave-uniform
        #pragma unroll
        for (int c4 = 0; c4 < 12; ++c4) {
            float4 av = ar[c4];
            acc[4*c4+0] += wv*av.x; acc[4*c4+1] += wv*av.y;
            acc[4*c4+2] += wv*av.z; acc[4*c4+3] += wv*av.w;
        }
    }
    #pragma unroll
    for (int cI = 0; cI < 48; ++cI) sh[t*49 + cI] = acc[cI];
    __syncthreads();
    if (t < 144) {
        int b = t / 9, r = t % 9, p = r / 3, q = r % 3;
        int colp = b*3 + p, colq = b*3 + q;
        const float* cp = c + (size_t)jb*48 + colq;
        float s = 0.f;
        for (int j0 = 0; j0 < 256; ++j0)
            s += sh[j0*49 + colp] * cp[j0*48];
        atomicAdd(&out[b*9 + p*3 + q], s);
    }
}

extern "C" void kernel_launch(void* const* d_in, const int* in_sizes, int n_in,
                              void* d_out, int out_size, void* d_ws, size_t ws_size,
                              hipStream_t stream) {
    const float* F     = (const float*)d_in[0];
    const float* pos   = (const float*)d_in[1];
    const int*   esrc  = (const int*)d_in[2];
    const int*   edst  = (const int*)d_in[3];
    const int*   etyp  = (const int*)d_in[4];
    const float* W_in  = (const float*)d_in[5];
    const float* fc1_0 = (const float*)d_in[6];
    const float* fc2_0 = (const float*)d_in[7];
    const float* W_0   = (const float*)d_in[8];
    const float* fc1_1 = (const float*)d_in[9];
    const float* fc2_1 = (const float*)d_in[10];
    const float* W_1   = (const float*)d_in[11];
    const float* W_out = (const float*)d_in[12];
    const float* w2    = (const float*)d_in[13];
    float* out = (float*)d_out;

    float* ws   = (float*)d_ws;
    float* ew   = ws;                     // 6
    float* G    = ws + 16;                // 768
    float* invF = ws + 800;               // 144
    float* bufA = ws + 1024;              // N*256
    float* bufB = bufA + N_NODES*BH;      // N*256
    float* hout = bufB + N_NODES*BH;      // N*48
    float* aArr = hout + N_NODES*48;      // N*48
    float* cArr = aArr + N_NODES*48;      // N*48
    int* cnt    = (int*)(cArr + N_NODES*48);
    int* off    = cnt + N_NODES;          // N+1
    int* cursor = off + N_NODES + 1;      // N
    int* sedge  = cursor + N_NODES;       // E

    setup_kernel<<<1, 256, 0, stream>>>(F, W_in, fc1_0, fc2_0, fc1_1, fc2_1, ew, G, invF, out);
    h0_kernel<<<1024, 256, 0, stream>>>(pos, G, bufA);
    zero_kernel<<<16, 256, 0, stream>>>(cnt, N_NODES);
    hist_kernel<<<512, 256, 0, stream>>>(edst, cnt);
    scan_kernel<<<1, 256, 0, stream>>>(cnt, off, cursor);
    fill_kernel<<<512, 256, 0, stream>>>(esrc, edst, etyp, cursor, sedge);
    layer_kernel<<<1024, 256, 0, stream>>>(bufA, bufB, off, sedge, ew,     W_0);
    layer_kernel<<<1024, 256, 0, stream>>>(bufB, bufA, off, sedge, ew + 3, W_1);
    hout_kernel<<<256, 256, 0, stream>>>(bufA, W_out, hout);
    ac_kernel<<<256, 256, 0, stream>>>(hout, esrc, edst, invF, aArr, cArr);
    stress_kernel<<<512, 256, 0, stream>>>(w2, aArr, cArr, out);
}